// Round 1
// baseline (445.404 us; speedup 1.0000x reference)
//
#include <hip/hip_runtime.h>
#include <math.h>

#define HH   1024
#define TT   2048
#define BB   32
#define NC   16            // chunks along T  -> 32*16 = 512 blocks
#define TC   (TT / NC)     // 128 timesteps per chunk
#define NTH  256           // each thread owns one float4 of H
#define TUN  4             // timesteps per reduction round

// ---------------- kernel 0: v[h] = sum_k W_v[k] * W_attn[k, H+h] ----------------
__global__ __launch_bounds__(NTH) void compute_v_kernel(
    const float* __restrict__ W_attn, const float* __restrict__ W_v,
    float* __restrict__ v_out)
{
    const int h = blockIdx.x * NTH + threadIdx.x;
    const float* col = W_attn + HH + h;   // row stride 2H
    float s = 0.f;
#pragma unroll 8
    for (int k = 0; k < HH; ++k)
        s = fmaf(W_v[k], col[(size_t)k * (2 * HH)], s);
    v_out[h] = s;
}

// ---------------- kernel 1: fused score + online softmax + weighted sum ----------
__global__ __launch_bounds__(NTH) void attn_pass_kernel(
    const float* __restrict__ enc, const float* __restrict__ v,
    float* __restrict__ ws_m, float* __restrict__ ws_l,
    float* __restrict__ ws_acc)
{
    const int c    = blockIdx.x;
    const int b    = blockIdx.y;
    const int tid  = threadIdx.x;
    const int lane = tid & 63;
    const int wave = tid >> 6;

    const float4 v4 = reinterpret_cast<const float4*>(v)[tid];
    const float4* enc4 = reinterpret_cast<const float4*>(enc)
                         + ((size_t)b * TT + (size_t)c * TC) * (HH / 4);

    __shared__ float red[TUN][4];

    float  m = -INFINITY;
    float  l = 0.f;
    float4 acc = make_float4(0.f, 0.f, 0.f, 0.f);

    for (int t0 = 0; t0 < TC; t0 += TUN) {
        float4 e[TUN];
        float  p[TUN];
#pragma unroll
        for (int i = 0; i < TUN; ++i)
            e[i] = enc4[(size_t)(t0 + i) * (HH / 4) + tid];

#pragma unroll
        for (int i = 0; i < TUN; ++i) {
            p[i] = e[i].x * v4.x + e[i].y * v4.y + e[i].z * v4.z + e[i].w * v4.w;
#pragma unroll
            for (int off = 32; off > 0; off >>= 1)
                p[i] += __shfl_down(p[i], off, 64);
        }
        if (lane == 0) {
#pragma unroll
            for (int i = 0; i < TUN; ++i) red[i][wave] = p[i];
        }
        __syncthreads();

        float s[TUN];
        float mn = m;
#pragma unroll
        for (int i = 0; i < TUN; ++i) {
            s[i] = red[i][0] + red[i][1] + red[i][2] + red[i][3];
            mn = fmaxf(mn, s[i]);
        }
        __syncthreads();   // protect red[] reuse next round

        const float alpha = __expf(m - mn);   // m=-inf first iter -> alpha=0
        float w[TUN];
        float wsum = 0.f;
#pragma unroll
        for (int i = 0; i < TUN; ++i) { w[i] = __expf(s[i] - mn); wsum += w[i]; }

        l = l * alpha + wsum;
        acc.x *= alpha; acc.y *= alpha; acc.z *= alpha; acc.w *= alpha;
#pragma unroll
        for (int i = 0; i < TUN; ++i) {
            acc.x = fmaf(w[i], e[i].x, acc.x);
            acc.y = fmaf(w[i], e[i].y, acc.y);
            acc.z = fmaf(w[i], e[i].z, acc.z);
            acc.w = fmaf(w[i], e[i].w, acc.w);
        }
        m = mn;
    }

    const int idx = b * NC + c;
    if (tid == 0) { ws_m[idx] = m; ws_l[idx] = l; }
    reinterpret_cast<float4*>(ws_acc + (size_t)idx * HH)[tid] = acc;
}

// ---------------- kernel 2: combine chunk partials ----------------
__global__ __launch_bounds__(NTH) void combine_kernel(
    const float* __restrict__ ws_m, const float* __restrict__ ws_l,
    const float* __restrict__ ws_acc, float* __restrict__ out)
{
    const int b   = blockIdx.x;
    const int tid = threadIdx.x;

    float M = -INFINITY;
#pragma unroll
    for (int c = 0; c < NC; ++c) M = fmaxf(M, ws_m[b * NC + c]);

    float sc[NC];
    float L = 0.f;
#pragma unroll
    for (int c = 0; c < NC; ++c) {
        sc[c] = __expf(ws_m[b * NC + c] - M);
        L = fmaf(sc[c], ws_l[b * NC + c], L);
    }

    float4 r = make_float4(0.f, 0.f, 0.f, 0.f);
#pragma unroll
    for (int c = 0; c < NC; ++c) {
        const float4 a =
            reinterpret_cast<const float4*>(ws_acc + (size_t)(b * NC + c) * HH)[tid];
        r.x = fmaf(sc[c], a.x, r.x);
        r.y = fmaf(sc[c], a.y, r.y);
        r.z = fmaf(sc[c], a.z, r.z);
        r.w = fmaf(sc[c], a.w, r.w);
    }
    const float inv = 1.f / L;
    reinterpret_cast<float4*>(out + (size_t)b * HH)[tid] =
        make_float4(r.x * inv, r.y * inv, r.z * inv, r.w * inv);
}

extern "C" void kernel_launch(void* const* d_in, const int* in_sizes, int n_in,
                              void* d_out, int out_size, void* d_ws, size_t ws_size,
                              hipStream_t stream) {
    // inputs: 0 encoder_outputs (B,T,H) f32 | 1 hidden | 2 W_attn (H,2H) f32
    //         3 b_attn | 4 W_v (1,H) f32 | 5 b_v
    // hidden / b_attn / b_v cancel under softmax shift-invariance -> unused.
    const float* enc    = (const float*)d_in[0];
    const float* W_attn = (const float*)d_in[2];
    const float* W_v    = (const float*)d_in[4];
    float* out = (float*)d_out;

    float* ws     = (float*)d_ws;
    float* v      = ws;                 // 1024 floats
    float* ws_m   = ws + 1024;          // 512 floats
    float* ws_l   = ws + 1536;          // 512 floats
    float* ws_acc = ws + 2048;          // 32*16*1024 floats (~2 MB)

    compute_v_kernel<<<HH / NTH, NTH, 0, stream>>>(W_attn, W_v, v);
    attn_pass_kernel<<<dim3(NC, BB), NTH, 0, stream>>>(enc, v, ws_m, ws_l, ws_acc);
    combine_kernel<<<BB, NTH, 0, stream>>>(ws_m, ws_l, ws_acc, out);
}

// Round 3
// 380.318 us; speedup vs baseline: 1.1711x; 1.1711x over previous
//
#include <hip/hip_runtime.h>
#include <math.h>

#define HH   1024
#define TT   2048
#define BB   32
#define NC   32            // chunks along T  -> 32*32 = 1024 blocks (4 blocks/CU)
#define TC   (TT / NC)     // 64 timesteps per block
#define NWV  4             // waves per block
#define TPW  (TC / NWV)    // 16 timesteps per wave
#define NTH  (NWV * 64)    // 256 threads
#define KSL  16            // k-slices for compute_v partials

// ---------------- kernel 0a: vpart[ks][h] = sum_{k in slice} W_v[k]*W_attn[k,H+h] ----
__global__ __launch_bounds__(256) void compute_v_part(
    const float* __restrict__ W_attn, const float* __restrict__ W_v,
    float* __restrict__ vpart)
{
    const int h  = blockIdx.x * 256 + threadIdx.x;   // blockIdx.x in [0,4)
    const int ks = blockIdx.y;                       // [0,KSL)
    const int k0 = ks * (HH / KSL);
    const float* col = W_attn + HH + h;
    float s = 0.f;
#pragma unroll 8
    for (int k = k0; k < k0 + HH / KSL; ++k)
        s = fmaf(W_v[k], col[(size_t)k * (2 * HH)], s);
    vpart[ks * HH + h] = s;
}

// ---------------- kernel 0b: v[h] = sum_ks vpart[ks][h] ----------------
__global__ __launch_bounds__(256) void compute_v_reduce(
    const float* __restrict__ vpart, float* __restrict__ v_out)
{
    const int h = blockIdx.x * 256 + threadIdx.x;
    float s = 0.f;
#pragma unroll
    for (int ks = 0; ks < KSL; ++ks) s += vpart[ks * HH + h];
    v_out[h] = s;
}

// ---------------- kernel 1: fused score + online softmax + weighted sum ----------
// Wave-private: each wave covers full H (lane owns 16 floats), handles TPW
// contiguous timesteps with zero barriers in the hot loop; one LDS merge at end.
__global__ __launch_bounds__(NTH) void attn_pass_kernel(
    const float* __restrict__ enc, const float* __restrict__ v,
    float* __restrict__ ws_m, float* __restrict__ ws_l,
    float* __restrict__ ws_acc)
{
    const int c    = blockIdx.x;
    const int b    = blockIdx.y;
    const int tid  = threadIdx.x;
    const int lane = tid & 63;
    const int wave = tid >> 6;

    // lane's H ownership: float4 slots lane, lane+64, lane+128, lane+192
    float4 v4[4];
#pragma unroll
    for (int j = 0; j < 4; ++j)
        v4[j] = reinterpret_cast<const float4*>(v)[lane + 64 * j];

    const int t0 = c * TC + wave * TPW;
    const float4* enc4 = reinterpret_cast<const float4*>(enc)
                         + ((size_t)b * TT + t0) * (HH / 4);

    float  m = -INFINITY;
    float  l = 0.f;
    float4 acc[4] = {make_float4(0,0,0,0), make_float4(0,0,0,0),
                     make_float4(0,0,0,0), make_float4(0,0,0,0)};

    float4 e[4];
#pragma unroll
    for (int j = 0; j < 4; ++j) e[j] = enc4[lane + 64 * j];

    for (int i = 0; i < TPW; ++i) {
        float4 en[4];
        const bool more = (i + 1 < TPW);
        if (more) {
#pragma unroll
            for (int j = 0; j < 4; ++j)
                en[j] = enc4[(size_t)(i + 1) * (HH / 4) + lane + 64 * j];
        }
        // dot(enc_t, v) partial on this lane
        float p = 0.f;
#pragma unroll
        for (int j = 0; j < 4; ++j) {
            p = fmaf(e[j].x, v4[j].x, p);
            p = fmaf(e[j].y, v4[j].y, p);
            p = fmaf(e[j].z, v4[j].z, p);
            p = fmaf(e[j].w, v4[j].w, p);
        }
        // butterfly all-reduce across 64 lanes
#pragma unroll
        for (int off = 1; off < 64; off <<= 1)
            p += __shfl_xor(p, off, 64);

        const float mn    = fmaxf(m, p);
        const float alpha = __expf(m - mn);   // first iter: exp(-inf)=0
        const float w     = __expf(p - mn);
        l = fmaf(l, alpha, w);
#pragma unroll
        for (int j = 0; j < 4; ++j) {
            acc[j].x = fmaf(acc[j].x, alpha, w * e[j].x);
            acc[j].y = fmaf(acc[j].y, alpha, w * e[j].y);
            acc[j].z = fmaf(acc[j].z, alpha, w * e[j].z);
            acc[j].w = fmaf(acc[j].w, alpha, w * e[j].w);
        }
        m = mn;
        if (more) {
#pragma unroll
            for (int j = 0; j < 4; ++j) e[j] = en[j];
        }
    }

    // ---- block-level merge of the 4 wave-private (m, l, acc) ----
    __shared__ float sm[NWV], sl[NWV];
    __shared__ float4 sacc[NWV * 256];   // 16 KB

    if (lane == 0) { sm[wave] = m; sl[wave] = l; }
    __syncthreads();

    float M = -INFINITY;
#pragma unroll
    for (int w2 = 0; w2 < NWV; ++w2) M = fmaxf(M, sm[w2]);
    const float myscale = __expf(m - M);

#pragma unroll
    for (int j = 0; j < 4; ++j) {
        float4 a = acc[j];
        a.x *= myscale; a.y *= myscale; a.z *= myscale; a.w *= myscale;
        sacc[wave * 256 + lane + 64 * j] = a;
    }
    __syncthreads();

    // thread tid reduces float4-slot `tid` across the 4 waves
    float4 r = make_float4(0, 0, 0, 0);
#pragma unroll
    for (int w2 = 0; w2 < NWV; ++w2) {
        const float4 a = sacc[w2 * 256 + tid];
        r.x += a.x; r.y += a.y; r.z += a.z; r.w += a.w;
    }

    const int idx = b * NC + c;
    reinterpret_cast<float4*>(ws_acc + (size_t)idx * HH)[tid] = r;
    if (tid == 0) {
        float L = 0.f;
#pragma unroll
        for (int w2 = 0; w2 < NWV; ++w2) L = fmaf(sl[w2], __expf(sm[w2] - M), L);
        ws_m[idx] = M;
        ws_l[idx] = L;
    }
}

// ---------------- kernel 2: combine chunk partials ----------------
__global__ __launch_bounds__(256) void combine_kernel(
    const float* __restrict__ ws_m, const float* __restrict__ ws_l,
    const float* __restrict__ ws_acc, float* __restrict__ out)
{
    const int b   = blockIdx.x;
    const int tid = threadIdx.x;

    float M = -INFINITY;
#pragma unroll
    for (int c = 0; c < NC; ++c) M = fmaxf(M, ws_m[b * NC + c]);

    float L = 0.f;
    float4 r = make_float4(0, 0, 0, 0);
#pragma unroll
    for (int c = 0; c < NC; ++c) {
        const float sc = __expf(ws_m[b * NC + c] - M);
        L = fmaf(sc, ws_l[b * NC + c], L);
        const float4 a =
            reinterpret_cast<const float4*>(ws_acc + (size_t)(b * NC + c) * HH)[tid];
        r.x = fmaf(sc, a.x, r.x);
        r.y = fmaf(sc, a.y, r.y);
        r.z = fmaf(sc, a.z, r.z);
        r.w = fmaf(sc, a.w, r.w);
    }
    const float inv = 1.f / L;
    reinterpret_cast<float4*>(out + (size_t)b * HH)[tid] =
        make_float4(r.x * inv, r.y * inv, r.z * inv, r.w * inv);
}

extern "C" void kernel_launch(void* const* d_in, const int* in_sizes, int n_in,
                              void* d_out, int out_size, void* d_ws, size_t ws_size,
                              hipStream_t stream) {
    // inputs: 0 encoder_outputs (B,T,H) f32 | 1 hidden | 2 W_attn (H,2H) f32
    //         3 b_attn | 4 W_v (1,H) f32 | 5 b_v
    // hidden / b_attn / b_v are constant in t -> cancel under softmax.
    const float* enc    = (const float*)d_in[0];
    const float* W_attn = (const float*)d_in[2];
    const float* W_v    = (const float*)d_in[4];
    float* out = (float*)d_out;

    float* ws     = (float*)d_ws;
    float* v      = ws;                          // 1024
    float* vpart  = ws + 1024;                   // 16*1024
    float* ws_m   = ws + 1024 + KSL * HH;        // 1024
    float* ws_l   = ws_m + BB * NC;              // 1024
    float* ws_acc = ws_l + BB * NC;              // 32*32*1024 = 4 MB

    compute_v_part<<<dim3(4, KSL), 256, 0, stream>>>(W_attn, W_v, vpart);
    compute_v_reduce<<<HH / 256, 256, 0, stream>>>(vpart, v);
    attn_pass_kernel<<<dim3(NC, BB), NTH, 0, stream>>>(enc, v, ws_m, ws_l, ws_acc);
    combine_kernel<<<BB, 256, 0, stream>>>(ws_m, ws_l, ws_acc, out);
}